// Round 15
// baseline (122.343 us; speedup 1.0000x reference)
//
#include <hip/hip_runtime.h>

typedef _Float16 f16;
typedef _Float16 f16x4 __attribute__((ext_vector_type(4)));
typedef _Float16 f16x8 __attribute__((ext_vector_type(8)));
typedef float f32x4 __attribute__((ext_vector_type(4)));

#define L2E 1.44269504088896340736f

constexpr int D  = 512;
constexpr int S  = 1024;
constexpr int B  = 4;
constexpr int BS = B * S;   // 4096

// workspace layout (bytes); total ~27.3 MB
constexpr size_t OFF_WT   = 0;                               // 4 * 512*512 f16 (WqT,WkT,WvT,WoT)
constexpr size_t OFF_Q16  = OFF_WT  + 4ull * D * D * 2;
constexpr size_t OFF_K16  = OFF_Q16 + (size_t)BS * D * 2;
constexpr size_t OFF_VT   = OFF_K16 + (size_t)BS * D * 2;    // v, transposed: [b*512+n][S]
constexpr size_t OFF_AT   = OFF_VT  + (size_t)BS * D * 2;    // attention output f16 [BS][D]
constexpr size_t OFF_TAB  = OFF_AT  + (size_t)BS * D * 2;    // float [8][1032]
constexpr size_t OFF_COEF = OFF_TAB + 8ull * 1032 * 4;       // float c[8], d[8]; int flag[8]
constexpr size_t OFF_TDH  = OFF_COEF + 256;                  // f16 td, col-permuted, 8.4 MB

// ---------------------------------------------------------------------------
// Kernel 1 "prep_small": weight transpose+cvt (256 blocks) + bias LUT +
// analytic linearity detection (1 block).
// ---------------------------------------------------------------------------
__global__ __launch_bounds__(256) void prep_small(
    const float* __restrict__ Wq, const float* __restrict__ Wk,
    const float* __restrict__ Wv, const float* __restrict__ Wo,
    f16* __restrict__ WT,
    const float* __restrict__ Wt1, const float* __restrict__ bt1,
    const float* __restrict__ Wt2, const float* __restrict__ bt2,
    float* __restrict__ tab, float* __restrict__ coef)
{
    __shared__ float tile[64][65];
    __shared__ float w1s[32], b1s[32], w2s[256], b2s[8];

    const int bx = blockIdx.x;
    const int t = threadIdx.x;

    if (bx < 256) {
        // ---- weight transpose ----
        const int z = bx >> 6, xy = bx & 63;
        const float* __restrict__ W = (z == 0) ? Wq : (z == 1) ? Wk : (z == 2) ? Wv : Wo;
        f16* __restrict__ out = WT + (size_t)z * D * D;
        const int k0 = (xy >> 3) * 64, n0 = (xy & 7) * 64;
        for (int i = t; i < 4096; i += 256) {
            int r = i >> 6, c = i & 63;
            tile[r][c] = W[(size_t)(k0 + r) * D + n0 + c];
        }
        __syncthreads();
        for (int i = t; i < 4096; i += 256) {
            int nn = i >> 6, kk = i & 63;
            out[(size_t)(n0 + nn) * D + k0 + kk] = (f16)tile[kk][nn];
        }
    } else {
        // ---- bias LUT + coef/flag (no atomics) ----
        if (t < 32) { w1s[t] = Wt1[t]; b1s[t] = bt1[t]; }
        w2s[t] = Wt2[t];
        if (t < 8) b2s[t] = bt2[t];
        __syncthreads();

        const int hh = t >> 5, j = t & 31;

        float f0 = b2s[hh], f1 = b2s[hh];
#pragma unroll 4
        for (int jj = 0; jj < 32; ++jj) {
            float w2 = w2s[jj * 8 + hh];
            f0 += fmaxf(b1s[jj], 0.f) * w2;
            f1 += fmaxf(w1s[jj] + b1s[jj], 0.f) * w2;
        }

        // exact max deviation of the PWL from the chord: check breakpoint u_j
        float devj = 0.f;
        {
            float w1 = w1s[j], b1 = b1s[j];
            float u = (w1 != 0.f) ? (-b1 / w1) : -1.f;
            if (u > 0.f && u < 1.f) {
                float fu = b2s[hh];
#pragma unroll 4
                for (int jj = 0; jj < 32; ++jj)
                    fu += fmaxf(fmaf(u, w1s[jj], b1s[jj]), 0.f) * w2s[jj * 8 + hh];
                devj = fabsf(fu - fmaf(u, f1 - f0, f0)) * L2E;
            }
        }
#pragma unroll
        for (int m = 1; m < 32; m <<= 1)
            devj = fmaxf(devj, __shfl_xor(devj, m));

        if (j == 0) {
            coef[hh]     = (f1 - f0) * L2E;
            coef[8 + hh] = f0 * L2E;
            ((int*)coef)[16 + hh] = (devj < 1e-4f) ? 1 : 0;
        }

        // LUT for the general nonlinear path
        for (int idx = t; idx <= 1024; idx += 256) {
            float tdv = (float)idx * (1.0f / 1024.0f);
            float acc[8];
#pragma unroll
            for (int h2 = 0; h2 < 8; ++h2) acc[h2] = b2s[h2];
#pragma unroll 4
            for (int jj = 0; jj < 32; ++jj) {
                float hvv = fmaxf(fmaf(tdv, w1s[jj], b1s[jj]), 0.f);
#pragma unroll
                for (int h2 = 0; h2 < 8; ++h2) acc[h2] += hvv * w2s[jj * 8 + h2];
            }
#pragma unroll
            for (int h2 = 0; h2 < 8; ++h2)
                tab[h2 * 1032 + idx] = acc[h2] * L2E;
        }
    }
}

// ---------------------------------------------------------------------------
// Kernel 2 "proj_plus": heterogeneous dispatch (R12).
// bid < 384: fused q/k/v projection GEMM, 128x128 tile.
// bid >= 384: td f32->f16 convert (2048 memory-bound blocks co-executing).
// ---------------------------------------------------------------------------
__global__ __launch_bounds__(256) void proj_plus(
    const float* __restrict__ Aq, const float* __restrict__ Ak, const float* __restrict__ Av,
    const f16* __restrict__ WT,
    const float* __restrict__ bq, const float* __restrict__ bk, const float* __restrict__ bv,
    f16* __restrict__ q16, f16* __restrict__ k16, f16* __restrict__ vT, float qscale,
    const float* __restrict__ td, f16* __restrict__ tdh)
{
    __shared__ f16 As[2][128][40];
    __shared__ f16 Bs[2][128][40];

    const int bid = blockIdx.x;
    const int t = threadIdx.x;

    if (bid >= 384) {
        // ---- td convert+permute: chunk = 8 dest f16 ----
        const int chunk = (bid - 384) * 256 + t;      // [0, 524288)
        const int row = chunk >> 7;                   // 4096 rows, 128 chunks each
        const int c7 = chunk & 127;
        const int tl = c7 >> 2, gg = c7 & 3;
        const float* __restrict__ src = td + (size_t)row * S + tl * 32;
        float4 a = *reinterpret_cast<const float4*>(src + gg * 4);
        float4 c = *reinterpret_cast<const float4*>(src + 16 + gg * 4);
        f16x8 hv;
        hv[0] = (f16)a.x; hv[1] = (f16)a.y; hv[2] = (f16)a.z; hv[3] = (f16)a.w;
        hv[4] = (f16)c.x; hv[5] = (f16)c.y; hv[6] = (f16)c.z; hv[7] = (f16)c.w;
        *reinterpret_cast<f16x8*>(tdh + (size_t)chunk * 8) = hv;
        return;
    }

    // ---- proj GEMM: decode (x,y,z) from linear bid ----
    const int bx = bid & 31, by = (bid >> 5) & 3, z = bid >> 7;
    const float* __restrict__ A    = (z == 0) ? Aq : (z == 1) ? Ak : Av;
    const float* __restrict__ bias = (z == 0) ? bq : (z == 1) ? bk : bv;
    const f16* __restrict__ W      = WT + (size_t)z * D * D;
    const float scale = (z == 0) ? qscale : 1.0f;

    const int l = t & 63, w = t >> 6;
    const int i16 = l & 15, g = l >> 4;
    const int wm = w >> 1, wn = w & 1;
    const int m0 = bx * 128, n0 = by * 128;

    f32x4 acc[4][4] = {};

    float4 ar[4];
    f16x8  br[2];

    auto load_stage = [&](int kt) {
        const int k0 = kt * 32;
#pragma unroll
        for (int r = 0; r < 4; ++r) {
            int ch = t + 256 * r, row = ch >> 3, c4 = ch & 7;
            ar[r] = *reinterpret_cast<const float4*>(A + (size_t)(m0 + row) * D + k0 + c4 * 4);
        }
#pragma unroll
        for (int r = 0; r < 2; ++r) {
            int ch = t + 256 * r, row = ch >> 2, c8 = ch & 3;
            br[r] = *reinterpret_cast<const f16x8*>(W + (size_t)(n0 + row) * D + k0 + c8 * 8);
        }
    };
    auto write_stage = [&](int buf) {
#pragma unroll
        for (int r = 0; r < 4; ++r) {
            int ch = t + 256 * r, row = ch >> 3, c4 = ch & 7;
            f16x4 hv;
            hv[0] = (f16)ar[r].x; hv[1] = (f16)ar[r].y; hv[2] = (f16)ar[r].z; hv[3] = (f16)ar[r].w;
            *reinterpret_cast<f16x4*>(&As[buf][row][c4 * 4]) = hv;
        }
#pragma unroll
        for (int r = 0; r < 2; ++r) {
            int ch = t + 256 * r, row = ch >> 2, c8 = ch & 3;
            *reinterpret_cast<f16x8*>(&Bs[buf][row][c8 * 8]) = br[r];
        }
    };

    load_stage(0);
    write_stage(0);
    __syncthreads();

    for (int kt = 0; kt < 16; ++kt) {
        const int cur = kt & 1;
        if (kt < 15) load_stage(kt + 1);

        f16x8 af[4], bf[4];
#pragma unroll
        for (int i = 0; i < 4; ++i)
            af[i] = *reinterpret_cast<const f16x8*>(&As[cur][wm * 64 + i * 16 + i16][g * 8]);
#pragma unroll
        for (int j = 0; j < 4; ++j)
            bf[j] = *reinterpret_cast<const f16x8*>(&Bs[cur][wn * 64 + j * 16 + i16][g * 8]);
#pragma unroll
        for (int i = 0; i < 4; ++i)
#pragma unroll
            for (int j = 0; j < 4; ++j)
                acc[i][j] = __builtin_amdgcn_mfma_f32_16x16x32_f16(af[i], bf[j], acc[i][j], 0, 0, 0);

        if (kt < 15) write_stage(cur ^ 1);
        __syncthreads();
    }

    float bvv[4];
#pragma unroll
    for (int j = 0; j < 4; ++j) bvv[j] = bias[n0 + wn * 64 + j * 16 + i16];

    if (z < 2) {
        f16* __restrict__ out = (z == 0) ? q16 : k16;
#pragma unroll
        for (int i = 0; i < 4; ++i) {
#pragma unroll
            for (int j = 0; j < 4; ++j) {
                const int nn = n0 + wn * 64 + j * 16 + i16;
#pragma unroll
                for (int e = 0; e < 4; ++e) {
                    const int mr = m0 + wm * 64 + i * 16 + g * 4 + e;
                    out[(size_t)mr * D + nn] = (f16)((acc[i][j][e] + bvv[j]) * scale);
                }
            }
        }
    } else {
        // transposed store: vT[(b*512 + n)*1024 + j_in_seq]
#pragma unroll
        for (int i = 0; i < 4; ++i) {
            const int mr = m0 + wm * 64 + i * 16 + g * 4;  // 4 consecutive rows via e
            const int bb = mr >> 10, jj = mr & 1023;
#pragma unroll
            for (int j = 0; j < 4; ++j) {
                const int nn = n0 + wn * 64 + j * 16 + i16;
                f16x4 hv;
#pragma unroll
                for (int e = 0; e < 4; ++e) hv[e] = (f16)(acc[i][j][e] + bvv[j]);
                *reinterpret_cast<f16x4*>(vT + ((size_t)(bb * D + nn)) * S + jj) = hv;
            }
        }
    }
}

// ---------------------------------------------------------------------------
// Kernel 3: fused flash attention with temporal bias.
// R14: occupancy via LDS shrink.  The epilogue merge buffers (obuf 17.4KB +
// mlb 0.5KB) are only touched AFTER the main loop's final barrier (which
// guarantees all K/V LDS reads are done) -> alias obuf onto Ks and mlb onto
// Vs.  LDS 58 -> 40KB => 4 blocks/CU (was 2).  __launch_bounds__(512, 8)
// caps VGPR at 64 so the wave limit doesn't bite (waves/CU halves at 64/128).
// Chain-bound kernel + 2x independent desynced blocks per SIMD -> more
// latency coverage (R9 1blk=46us vs R8 2blk=39us precedent).
// ---------------------------------------------------------------------------
__global__ __launch_bounds__(512, 8) void attn_kernel(
    const f16* __restrict__ q16, const f16* __restrict__ k16, const f16* __restrict__ vT,
    const f16* __restrict__ tdh, const float* __restrict__ tabg, const float* __restrict__ coef,
    f16* __restrict__ out16)
{
    __shared__ __align__(16) f16 Ks[2][2][2048];   // [dbuf][half][32*64]; epilogue: obuf alias
    __shared__ __align__(16) f16 Vs[2][2][2048];   // [dbuf][half][64*32]; epilogue: mlb alias
    __shared__ __align__(16) f16 Ps[8][512];

    const int bid = blockIdx.x;
    const int b  = bid & 3;
    const int h  = (bid >> 2) & 7;
    const int qt = bid >> 5;                 // [0,16)

    const int t = threadIdx.x;
    const int w = t >> 6, l = t & 63;
    const int i16 = l & 15, g = l >> 4;
    const int half = w >> 2, pr = w & 3;
    const int qrow = qt * 64 + pr * 16 + i16;

    const float cH = coef[h], dH = coef[8 + h];
    const int lin = ((const int*)coef)[16 + h];
    const float* __restrict__ th = tabg + h * 1032;

    f16x8 qf[2];
#pragma unroll
    for (int kf = 0; kf < 2; ++kf)
        qf[kf] = *reinterpret_cast<const f16x8*>(
            q16 + (size_t)(b * S + qrow) * D + h * 64 + kf * 32 + g * 8);

    float mr = -1e30f, lrp = 0.f;            // lrp = lane-partial l
    f32x4 o[4] = {};

    // staging: 512 threads, each 1 K-chunk + 1 V-chunk (16B) for half kh=t>>8
    const int kh   = t >> 8;
    const int krow = (t >> 3) & 31, kc8 = t & 7;
    const int vdv  = (t >> 2) & 63, vj8 = t & 3;
    const int kofs = krow * 64 + ((kc8 ^ (krow & 7)) << 3);
    const int vofs = vdv * 32 + ((vj8 ^ (vdv & 3)) << 3);
    f16x8 sk, sv;

    auto stage_load = [&](int jt) {
        sk = *reinterpret_cast<const f16x8*>(
            k16 + (size_t)(b * S + kh * 512 + jt * 32 + krow) * D + h * 64 + kc8 * 8);
        sv = *reinterpret_cast<const f16x8*>(
            vT + (size_t)(b * D + h * 64 + vdv) * S + kh * 512 + jt * 32 + vj8 * 8);
    };
    auto stage_write = [&](int buf) {
        *reinterpret_cast<f16x8*>(&Ks[buf][kh][kofs]) = sk;
        *reinterpret_cast<f16x8*>(&Vs[buf][kh][vofs]) = sv;
    };

    // swizzled LDS read offsets
    int kro0[2], kro1[2], vro[4];
#pragma unroll
    for (int fj = 0; fj < 2; ++fj) {
        const int rj = fj * 16 + i16;
        kro0[fj] = rj * 64 + ((g ^ (i16 & 7)) << 3);
        kro1[fj] = rj * 64 + (((g + 4) ^ (i16 & 7)) << 3);
    }
#pragma unroll
    for (int fv = 0; fv < 4; ++fv)
        vro[fv] = (fv * 16 + i16) * 32 + ((g ^ (i16 & 3)) << 3);

    const int q2  = (i16 >> 1) & 3;
    const int pw0 = i16 * 32 + ((((g >> 1)    ) ^ q2) << 3) + ((g & 1) << 2);
    const int pw1 = i16 * 32 + ((((g >> 1) + 2) ^ q2) << 3) + ((g & 1) << 2);
    const int prd = i16 * 32 + ((g ^ q2) << 3);

    const f16* __restrict__ tdp = tdh + (size_t)(b * S + qrow) * S + half * 512 + g * 8;
    f16x8 tcur, tnext;

    stage_load(0);
    tcur = *reinterpret_cast<const f16x8*>(tdp);
    stage_write(0);
    __syncthreads();

    for (int jt = 0; jt < 16; ++jt) {
        const int cur = jt & 1;
        if (jt < 15) {
            stage_load(jt + 1);
            tnext = *reinterpret_cast<const f16x8*>(tdp + (jt + 1) * 32);
        }

        // ---- S^T = K * Q^T ----
        f32x4 s[2];
        __builtin_amdgcn_s_setprio(1);
#pragma unroll
        for (int fj = 0; fj < 2; ++fj) {
            f16x8 ka0 = *reinterpret_cast<const f16x8*>(&Ks[cur][half][kro0[fj]]);
            f16x8 ka1 = *reinterpret_cast<const f16x8*>(&Ks[cur][half][kro1[fj]]);
            f32x4 zz = {0.f, 0.f, 0.f, 0.f};
            zz = __builtin_amdgcn_mfma_f32_16x16x32_f16(ka0, qf[0], zz, 0, 0, 0);
            s[fj] = __builtin_amdgcn_mfma_f32_16x16x32_f16(ka1, qf[1], zz, 0, 0, 0);
        }
        __builtin_amdgcn_s_setprio(0);

        // ---- bias + per-lane max (no cross-lane in steady state) ----
        float pvv[2][4];
        float tmax = -1e30f;
#pragma unroll
        for (int fj = 0; fj < 2; ++fj)
#pragma unroll
            for (int e = 0; e < 4; ++e) {
                float u = (float)tcur[fj * 4 + e];
                float vsc;
                if (lin) {
                    vsc = fmaf(u, cH, s[fj][e] + dH);
                } else {
                    float x = fminf(fmaxf(u, 0.f), 1.f) * 1024.f;
                    int ix = (int)x;
                    ix = (ix > 1023) ? 1023 : ix;
                    float fr = x - (float)ix;
                    float t0v = th[ix], t1v = th[ix + 1];
                    vsc = s[fj][e] + fmaf(fr, t1v - t0v, t0v);
                }
                pvv[fj][e] = vsc;
                tmax = fmaxf(tmax, vsc);
            }

        // deferred-max: only reduce+rescale when some lane exceeds mr + 8
        if (__any(tmax > mr + 8.f)) {
            tmax = fmaxf(tmax, __shfl_xor(tmax, 16));
            tmax = fmaxf(tmax, __shfl_xor(tmax, 32));
            if (tmax > mr) {
                float alpha = exp2f(mr - tmax);
                mr = tmax;
                lrp *= alpha;
#pragma unroll
                for (int fv = 0; fv < 4; ++fv) o[fv] *= alpha;
            }
        }

        // exp2 (bounded by 2^8), lane-partial l, pack P
        f16x4 pq[2];
#pragma unroll
        for (int fj = 0; fj < 2; ++fj)
#pragma unroll
            for (int e = 0; e < 4; ++e) {
                float p = exp2f(pvv[fj][e] - mr);
                lrp += p;
                pq[fj][e] = (f16)p;
            }

        f16* ps = Ps[w];
        *reinterpret_cast<f16x4*>(ps + pw0) = pq[0];
        *reinterpret_cast<f16x4*>(ps + pw1) = pq[1];
        f16x8 pb = *reinterpret_cast<const f16x8*>(ps + prd);

        // ---- out^T += V^T * P^T ----
        __builtin_amdgcn_s_setprio(1);
#pragma unroll
        for (int fv = 0; fv < 4; ++fv) {
            f16x8 va = *reinterpret_cast<const f16x8*>(&Vs[cur][half][vro[fv]]);
            o[fv] = __builtin_amdgcn_mfma_f32_16x16x32_f16(va, pb, o[fv], 0, 0, 0);
        }
        __builtin_amdgcn_s_setprio(0);

        if (jt < 15) stage_write(cur ^ 1);
        __syncthreads();
        tcur = tnext;
    }
    // After the jt=15 barrier above, ALL waves have finished every Ks/Vs read
    // of the main loop -> safe to reuse that LDS for the merge buffers.

    // epilogue cross-lane l reduction (lanes i16, +16, +32, +48 share a row)
    float lr = lrp;
    lr += __shfl_xor(lr, 16);
    lr += __shfl_xor(lr, 32);

    // ---- merge halves (flash-decoding combine), then store ----
    float* ob   = (float*)&Ks[0][0][0];      // [4 pairs][16 rows][64] floats = 16KB
    float* mlbp = (float*)&Vs[0][0][0];      // [4 pairs][2][16] floats = 512B
    if (half == 1) {
#pragma unroll
        for (int fv = 0; fv < 4; ++fv)
            *reinterpret_cast<f32x4*>(&ob[(pr * 16 + i16) * 64 + fv * 16 + g * 4]) = o[fv];
        if (g == 0) { mlbp[pr * 32 + i16] = mr; mlbp[pr * 32 + 16 + i16] = lr; }
    }
    __syncthreads();
    if (half == 0) {
        const float m1 = mlbp[pr * 32 + i16], l1 = mlbp[pr * 32 + 16 + i16];
        const float mm = fmaxf(mr, m1);
        const float a0 = exp2f(mr - mm), a1 = exp2f(m1 - mm);
        const float inv = 1.0f / (lr * a0 + l1 * a1);
#pragma unroll
        for (int fv = 0; fv < 4; ++fv) {
            f32x4 o1 = *reinterpret_cast<const f32x4*>(&ob[(pr * 16 + i16) * 64 + fv * 16 + g * 4]);
            f16x4 hv;
#pragma unroll
            for (int e = 0; e < 4; ++e) hv[e] = (f16)((o[fv][e] * a0 + o1[e] * a1) * inv);
            *reinterpret_cast<f16x4*>(
                out16 + (size_t)(b * S + qrow) * D + h * 64 + fv * 16 + g * 4) = hv;
        }
    }
}

// ---------------------------------------------------------------------------
// Kernel 4: output projection (unchanged).
// ---------------------------------------------------------------------------
__global__ __launch_bounds__(256) void final_gemm(const f16* __restrict__ A, const f16* __restrict__ WoT,
                                                  const float* __restrict__ bo, float* __restrict__ out)
{
    __shared__ f16 As[2][64][40];
    __shared__ f16 Bs[2][64][40];

    const int t = threadIdx.x;
    const int l = t & 63, w = t >> 6;
    const int i16 = l & 15, g = l >> 4;
    const int wm = w >> 1, wn = w & 1;
    const int m0 = blockIdx.x * 64, n0 = blockIdx.y * 64;

    f32x4 acc[2][2] = {};
    f16x8 ar, br;
    const int srow = t >> 2, sc8 = t & 3;

    auto load_stage = [&](int kt) {
        const int k0 = kt * 32;
        ar = *reinterpret_cast<const f16x8*>(A + (size_t)(m0 + srow) * D + k0 + sc8 * 8);
        br = *reinterpret_cast<const f16x8*>(WoT + (size_t)(n0 + srow) * D + k0 + sc8 * 8);
    };
    auto write_stage = [&](int buf) {
        *reinterpret_cast<f16x8*>(&As[buf][srow][sc8 * 8]) = ar;
        *reinterpret_cast<f16x8*>(&Bs[buf][srow][sc8 * 8]) = br;
    };

    load_stage(0);
    write_stage(0);
    __syncthreads();

    for (int kt = 0; kt < 16; ++kt) {
        const int cur = kt & 1;
        if (kt < 15) load_stage(kt + 1);

        f16x8 af[2], bf[2];
#pragma unroll
        for (int i = 0; i < 2; ++i)
            af[i] = *reinterpret_cast<const f16x8*>(&As[cur][wm * 32 + i * 16 + i16][g * 8]);
#pragma unroll
        for (int j = 0; j < 2; ++j)
            bf[j] = *reinterpret_cast<const f16x8*>(&Bs[cur][wn * 32 + j * 16 + i16][g * 8]);
#pragma unroll
        for (int i = 0; i < 2; ++i)
#pragma unroll
            for (int j = 0; j < 2; ++j)
                acc[i][j] = __builtin_amdgcn_mfma_f32_16x16x32_f16(af[i], bf[j], acc[i][j], 0, 0, 0);

        if (kt < 15) write_stage(cur ^ 1);
        __syncthreads();
    }

    float bvv[2];
#pragma unroll
    for (int j = 0; j < 2; ++j) bvv[j] = bo[n0 + wn * 32 + j * 16 + i16];

#pragma unroll
    for (int i = 0; i < 2; ++i) {
#pragma unroll
        for (int j = 0; j < 2; ++j) {
            const int nn = n0 + wn * 32 + j * 16 + i16;
#pragma unroll
            for (int e = 0; e < 4; ++e) {
                const int mr = m0 + wm * 32 + i * 16 + g * 4 + e;
                out[(size_t)mr * D + nn] = acc[i][j][e] + bvv[j];
            }
        }
    }
}

// ---------------------------------------------------------------------------
extern "C" void kernel_launch(void* const* d_in, const int* in_sizes, int n_in,
                              void* d_out, int out_size, void* d_ws, size_t ws_size,
                              hipStream_t stream)
{
    (void)in_sizes; (void)n_in; (void)out_size; (void)ws_size; // needs ~28 MB of ws

    const float* query = (const float*)d_in[0];
    const float* key_  = (const float*)d_in[1];
    const float* value = (const float*)d_in[2];
    const float* td    = (const float*)d_in[3];
    const float* Wq  = (const float*)d_in[4];  const float* bq  = (const float*)d_in[5];
    const float* Wk  = (const float*)d_in[6];  const float* bk  = (const float*)d_in[7];
    const float* Wv  = (const float*)d_in[8];  const float* bv  = (const float*)d_in[9];
    const float* Wo  = (const float*)d_in[10]; const float* bo  = (const float*)d_in[11];
    const float* Wt1 = (const float*)d_in[12]; const float* bt1 = (const float*)d_in[13];
    const float* Wt2 = (const float*)d_in[14]; const float* bt2 = (const float*)d_in[15];
    float* out = (float*)d_out;

    char* ws = (char*)d_ws;
    f16*   WT   = (f16*)(ws + OFF_WT);
    f16*   q16  = (f16*)(ws + OFF_Q16);
    f16*   k16  = (f16*)(ws + OFF_K16);
    f16*   vT   = (f16*)(ws + OFF_VT);
    f16*   at16 = (f16*)(ws + OFF_AT);
    float* tab  = (float*)(ws + OFF_TAB);
    float* coef = (float*)(ws + OFF_COEF);
    f16*   tdh  = (f16*)(ws + OFF_TDH);

    prep_small<<<257, 256, 0, stream>>>(Wq, Wk, Wv, Wo, WT,
                                        Wt1, bt1, Wt2, bt2, tab, coef);
    proj_plus<<<2432, 256, 0, stream>>>(query, key_, value, WT, bq, bk, bv,
                                        q16, k16, vT, 0.125f * L2E, td, tdh);
    attn_kernel<<<512, 512, 0, stream>>>(q16, k16, vT, tdh, tab, coef, at16);
    final_gemm<<<dim3(64, 8), 256, 0, stream>>>(at16, WT + 3ull * (size_t)D * D, bo, out);
}

// Round 16
// 65.789 us; speedup vs baseline: 1.8596x; 1.8596x over previous
//
#include <hip/hip_runtime.h>

typedef _Float16 f16;
typedef _Float16 f16x4 __attribute__((ext_vector_type(4)));
typedef _Float16 f16x8 __attribute__((ext_vector_type(8)));
typedef float f32x4 __attribute__((ext_vector_type(4)));

#define L2E 1.44269504088896340736f

constexpr int D  = 512;
constexpr int S  = 1024;
constexpr int B  = 4;
constexpr int BS = B * S;   // 4096

// workspace layout (bytes); total ~27.3 MB
constexpr size_t OFF_WT   = 0;                               // 4 * 512*512 f16 (WqT,WkT,WvT,WoT)
constexpr size_t OFF_Q16  = OFF_WT  + 4ull * D * D * 2;
constexpr size_t OFF_K16  = OFF_Q16 + (size_t)BS * D * 2;
constexpr size_t OFF_VT   = OFF_K16 + (size_t)BS * D * 2;    // v, transposed: [b*512+n][S]
constexpr size_t OFF_AT   = OFF_VT  + (size_t)BS * D * 2;    // attention output f16 [BS][D]
constexpr size_t OFF_TAB  = OFF_AT  + (size_t)BS * D * 2;    // float [8][1032]
constexpr size_t OFF_COEF = OFF_TAB + 8ull * 1032 * 4;       // float c[8], d[8]; int flag[8]
constexpr size_t OFF_TDH  = OFF_COEF + 256;                  // f16 td, col-permuted, 8.4 MB

// ---------------------------------------------------------------------------
// Kernel 1 "prep_small": weight transpose+cvt (256 blocks) + bias LUT +
// analytic linearity detection (1 block).
// ---------------------------------------------------------------------------
__global__ __launch_bounds__(256) void prep_small(
    const float* __restrict__ Wq, const float* __restrict__ Wk,
    const float* __restrict__ Wv, const float* __restrict__ Wo,
    f16* __restrict__ WT,
    const float* __restrict__ Wt1, const float* __restrict__ bt1,
    const float* __restrict__ Wt2, const float* __restrict__ bt2,
    float* __restrict__ tab, float* __restrict__ coef)
{
    __shared__ float tile[64][65];
    __shared__ float w1s[32], b1s[32], w2s[256], b2s[8];

    const int bx = blockIdx.x;
    const int t = threadIdx.x;

    if (bx < 256) {
        // ---- weight transpose ----
        const int z = bx >> 6, xy = bx & 63;
        const float* __restrict__ W = (z == 0) ? Wq : (z == 1) ? Wk : (z == 2) ? Wv : Wo;
        f16* __restrict__ out = WT + (size_t)z * D * D;
        const int k0 = (xy >> 3) * 64, n0 = (xy & 7) * 64;
        for (int i = t; i < 4096; i += 256) {
            int r = i >> 6, c = i & 63;
            tile[r][c] = W[(size_t)(k0 + r) * D + n0 + c];
        }
        __syncthreads();
        for (int i = t; i < 4096; i += 256) {
            int nn = i >> 6, kk = i & 63;
            out[(size_t)(n0 + nn) * D + k0 + kk] = (f16)tile[kk][nn];
        }
    } else {
        // ---- bias LUT + coef/flag (no atomics) ----
        if (t < 32) { w1s[t] = Wt1[t]; b1s[t] = bt1[t]; }
        w2s[t] = Wt2[t];
        if (t < 8) b2s[t] = bt2[t];
        __syncthreads();

        const int hh = t >> 5, j = t & 31;

        float f0 = b2s[hh], f1 = b2s[hh];
#pragma unroll 4
        for (int jj = 0; jj < 32; ++jj) {
            float w2 = w2s[jj * 8 + hh];
            f0 += fmaxf(b1s[jj], 0.f) * w2;
            f1 += fmaxf(w1s[jj] + b1s[jj], 0.f) * w2;
        }

        // exact max deviation of the PWL from the chord: check breakpoint u_j
        float devj = 0.f;
        {
            float w1 = w1s[j], b1 = b1s[j];
            float u = (w1 != 0.f) ? (-b1 / w1) : -1.f;
            if (u > 0.f && u < 1.f) {
                float fu = b2s[hh];
#pragma unroll 4
                for (int jj = 0; jj < 32; ++jj)
                    fu += fmaxf(fmaf(u, w1s[jj], b1s[jj]), 0.f) * w2s[jj * 8 + hh];
                devj = fabsf(fu - fmaf(u, f1 - f0, f0)) * L2E;
            }
        }
#pragma unroll
        for (int m = 1; m < 32; m <<= 1)
            devj = fmaxf(devj, __shfl_xor(devj, m));

        if (j == 0) {
            coef[hh]     = (f1 - f0) * L2E;
            coef[8 + hh] = f0 * L2E;
            ((int*)coef)[16 + hh] = (devj < 1e-4f) ? 1 : 0;
        }

        // LUT for the general nonlinear path
        for (int idx = t; idx <= 1024; idx += 256) {
            float tdv = (float)idx * (1.0f / 1024.0f);
            float acc[8];
#pragma unroll
            for (int h2 = 0; h2 < 8; ++h2) acc[h2] = b2s[h2];
#pragma unroll 4
            for (int jj = 0; jj < 32; ++jj) {
                float hvv = fmaxf(fmaf(tdv, w1s[jj], b1s[jj]), 0.f);
#pragma unroll
                for (int h2 = 0; h2 < 8; ++h2) acc[h2] += hvv * w2s[jj * 8 + h2];
            }
#pragma unroll
            for (int h2 = 0; h2 < 8; ++h2)
                tab[h2 * 1032 + idx] = acc[h2] * L2E;
        }
    }
}

// ---------------------------------------------------------------------------
// Kernel 2 "proj_plus": heterogeneous dispatch (R12).
// bid < 384: fused q/k/v projection GEMM, 128x128 tile.
// bid >= 384: td f32->f16 convert (2048 memory-bound blocks co-executing).
// ---------------------------------------------------------------------------
__global__ __launch_bounds__(256) void proj_plus(
    const float* __restrict__ Aq, const float* __restrict__ Ak, const float* __restrict__ Av,
    const f16* __restrict__ WT,
    const float* __restrict__ bq, const float* __restrict__ bk, const float* __restrict__ bv,
    f16* __restrict__ q16, f16* __restrict__ k16, f16* __restrict__ vT, float qscale,
    const float* __restrict__ td, f16* __restrict__ tdh)
{
    __shared__ f16 As[2][128][40];
    __shared__ f16 Bs[2][128][40];

    const int bid = blockIdx.x;
    const int t = threadIdx.x;

    if (bid >= 384) {
        // ---- td convert+permute: chunk = 8 dest f16 ----
        const int chunk = (bid - 384) * 256 + t;      // [0, 524288)
        const int row = chunk >> 7;                   // 4096 rows, 128 chunks each
        const int c7 = chunk & 127;
        const int tl = c7 >> 2, gg = c7 & 3;
        const float* __restrict__ src = td + (size_t)row * S + tl * 32;
        float4 a = *reinterpret_cast<const float4*>(src + gg * 4);
        float4 c = *reinterpret_cast<const float4*>(src + 16 + gg * 4);
        f16x8 hv;
        hv[0] = (f16)a.x; hv[1] = (f16)a.y; hv[2] = (f16)a.z; hv[3] = (f16)a.w;
        hv[4] = (f16)c.x; hv[5] = (f16)c.y; hv[6] = (f16)c.z; hv[7] = (f16)c.w;
        *reinterpret_cast<f16x8*>(tdh + (size_t)chunk * 8) = hv;
        return;
    }

    // ---- proj GEMM: decode (x,y,z) from linear bid ----
    const int bx = bid & 31, by = (bid >> 5) & 3, z = bid >> 7;
    const float* __restrict__ A    = (z == 0) ? Aq : (z == 1) ? Ak : Av;
    const float* __restrict__ bias = (z == 0) ? bq : (z == 1) ? bk : bv;
    const f16* __restrict__ W      = WT + (size_t)z * D * D;
    const float scale = (z == 0) ? qscale : 1.0f;

    const int l = t & 63, w = t >> 6;
    const int i16 = l & 15, g = l >> 4;
    const int wm = w >> 1, wn = w & 1;
    const int m0 = bx * 128, n0 = by * 128;

    f32x4 acc[4][4] = {};

    float4 ar[4];
    f16x8  br[2];

    auto load_stage = [&](int kt) {
        const int k0 = kt * 32;
#pragma unroll
        for (int r = 0; r < 4; ++r) {
            int ch = t + 256 * r, row = ch >> 3, c4 = ch & 7;
            ar[r] = *reinterpret_cast<const float4*>(A + (size_t)(m0 + row) * D + k0 + c4 * 4);
        }
#pragma unroll
        for (int r = 0; r < 2; ++r) {
            int ch = t + 256 * r, row = ch >> 2, c8 = ch & 3;
            br[r] = *reinterpret_cast<const f16x8*>(W + (size_t)(n0 + row) * D + k0 + c8 * 8);
        }
    };
    auto write_stage = [&](int buf) {
#pragma unroll
        for (int r = 0; r < 4; ++r) {
            int ch = t + 256 * r, row = ch >> 3, c4 = ch & 7;
            f16x4 hv;
            hv[0] = (f16)ar[r].x; hv[1] = (f16)ar[r].y; hv[2] = (f16)ar[r].z; hv[3] = (f16)ar[r].w;
            *reinterpret_cast<f16x4*>(&As[buf][row][c4 * 4]) = hv;
        }
#pragma unroll
        for (int r = 0; r < 2; ++r) {
            int ch = t + 256 * r, row = ch >> 2, c8 = ch & 3;
            *reinterpret_cast<f16x8*>(&Bs[buf][row][c8 * 8]) = br[r];
        }
    };

    load_stage(0);
    write_stage(0);
    __syncthreads();

    for (int kt = 0; kt < 16; ++kt) {
        const int cur = kt & 1;
        if (kt < 15) load_stage(kt + 1);

        f16x8 af[4], bf[4];
#pragma unroll
        for (int i = 0; i < 4; ++i)
            af[i] = *reinterpret_cast<const f16x8*>(&As[cur][wm * 64 + i * 16 + i16][g * 8]);
#pragma unroll
        for (int j = 0; j < 4; ++j)
            bf[j] = *reinterpret_cast<const f16x8*>(&Bs[cur][wn * 64 + j * 16 + i16][g * 8]);
#pragma unroll
        for (int i = 0; i < 4; ++i)
#pragma unroll
            for (int j = 0; j < 4; ++j)
                acc[i][j] = __builtin_amdgcn_mfma_f32_16x16x32_f16(af[i], bf[j], acc[i][j], 0, 0, 0);

        if (kt < 15) write_stage(cur ^ 1);
        __syncthreads();
    }

    float bvv[4];
#pragma unroll
    for (int j = 0; j < 4; ++j) bvv[j] = bias[n0 + wn * 64 + j * 16 + i16];

    if (z < 2) {
        f16* __restrict__ out = (z == 0) ? q16 : k16;
#pragma unroll
        for (int i = 0; i < 4; ++i) {
#pragma unroll
            for (int j = 0; j < 4; ++j) {
                const int nn = n0 + wn * 64 + j * 16 + i16;
#pragma unroll
                for (int e = 0; e < 4; ++e) {
                    const int mr = m0 + wm * 64 + i * 16 + g * 4 + e;
                    out[(size_t)mr * D + nn] = (f16)((acc[i][j][e] + bvv[j]) * scale);
                }
            }
        }
    } else {
        // transposed store: vT[(b*512 + n)*1024 + j_in_seq]
#pragma unroll
        for (int i = 0; i < 4; ++i) {
            const int mr = m0 + wm * 64 + i * 16 + g * 4;  // 4 consecutive rows via e
            const int bb = mr >> 10, jj = mr & 1023;
#pragma unroll
            for (int j = 0; j < 4; ++j) {
                const int nn = n0 + wn * 64 + j * 16 + i16;
                f16x4 hv;
#pragma unroll
                for (int e = 0; e < 4; ++e) hv[e] = (f16)(acc[i][j][e] + bvv[j]);
                *reinterpret_cast<f16x4*>(vT + ((size_t)(bb * D + nn)) * S + jj) = hv;
            }
        }
    }
}

// ---------------------------------------------------------------------------
// Kernel 3: fused flash attention with temporal bias (R13 exact — the best:
// R8 shell, deferred-max threshold 8, lane-partial l, setprio; separate
// 58KB merge buffers, launch_bounds(512,4) so VGPRs stay ~90, no spill.
// R14's forced-occupancy variant (launch_bounds(512,8) -> VGPR 32) spilled
// to scratch: FETCH 22->108MB, attn 36->86us.  Occupancy lever is dead.)
// ---------------------------------------------------------------------------
__global__ __launch_bounds__(512, 4) void attn_kernel(
    const f16* __restrict__ q16, const f16* __restrict__ k16, const f16* __restrict__ vT,
    const f16* __restrict__ tdh, const float* __restrict__ tabg, const float* __restrict__ coef,
    f16* __restrict__ out16)
{
    __shared__ __align__(16) f16 Ks[2][2][2048];   // [dbuf][half][32*64]
    __shared__ __align__(16) f16 Vs[2][2][2048];   // [dbuf][half][64*32]
    __shared__ __align__(16) f16 Ps[8][512];
    __shared__ float obuf[4][16][68];              // merge buffer (pairs)
    __shared__ float mlb[4][2][16];                // [pair][m|l][row]

    const int bid = blockIdx.x;
    const int b  = bid & 3;
    const int h  = (bid >> 2) & 7;
    const int qt = bid >> 5;                 // [0,16)

    const int t = threadIdx.x;
    const int w = t >> 6, l = t & 63;
    const int i16 = l & 15, g = l >> 4;
    const int half = w >> 2, pr = w & 3;
    const int qrow = qt * 64 + pr * 16 + i16;

    const float cH = coef[h], dH = coef[8 + h];
    const int lin = ((const int*)coef)[16 + h];
    const float* __restrict__ th = tabg + h * 1032;

    f16x8 qf[2];
#pragma unroll
    for (int kf = 0; kf < 2; ++kf)
        qf[kf] = *reinterpret_cast<const f16x8*>(
            q16 + (size_t)(b * S + qrow) * D + h * 64 + kf * 32 + g * 8);

    float mr = -1e30f, lrp = 0.f;            // lrp = lane-partial l
    f32x4 o[4] = {};

    // staging: 512 threads, each 1 K-chunk + 1 V-chunk (16B) for half kh=t>>8
    const int kh   = t >> 8;
    const int krow = (t >> 3) & 31, kc8 = t & 7;
    const int vdv  = (t >> 2) & 63, vj8 = t & 3;
    const int kofs = krow * 64 + ((kc8 ^ (krow & 7)) << 3);
    const int vofs = vdv * 32 + ((vj8 ^ (vdv & 3)) << 3);
    f16x8 sk, sv;

    auto stage_load = [&](int jt) {
        sk = *reinterpret_cast<const f16x8*>(
            k16 + (size_t)(b * S + kh * 512 + jt * 32 + krow) * D + h * 64 + kc8 * 8);
        sv = *reinterpret_cast<const f16x8*>(
            vT + (size_t)(b * D + h * 64 + vdv) * S + kh * 512 + jt * 32 + vj8 * 8);
    };
    auto stage_write = [&](int buf) {
        *reinterpret_cast<f16x8*>(&Ks[buf][kh][kofs]) = sk;
        *reinterpret_cast<f16x8*>(&Vs[buf][kh][vofs]) = sv;
    };

    // swizzled LDS read offsets
    int kro0[2], kro1[2], vro[4];
#pragma unroll
    for (int fj = 0; fj < 2; ++fj) {
        const int rj = fj * 16 + i16;
        kro0[fj] = rj * 64 + ((g ^ (i16 & 7)) << 3);
        kro1[fj] = rj * 64 + (((g + 4) ^ (i16 & 7)) << 3);
    }
#pragma unroll
    for (int fv = 0; fv < 4; ++fv)
        vro[fv] = (fv * 16 + i16) * 32 + ((g ^ (i16 & 3)) << 3);

    const int q2  = (i16 >> 1) & 3;
    const int pw0 = i16 * 32 + ((((g >> 1)    ) ^ q2) << 3) + ((g & 1) << 2);
    const int pw1 = i16 * 32 + ((((g >> 1) + 2) ^ q2) << 3) + ((g & 1) << 2);
    const int prd = i16 * 32 + ((g ^ q2) << 3);

    const f16* __restrict__ tdp = tdh + (size_t)(b * S + qrow) * S + half * 512 + g * 8;
    f16x8 tcur, tnext;

    stage_load(0);
    tcur = *reinterpret_cast<const f16x8*>(tdp);
    stage_write(0);
    __syncthreads();

    for (int jt = 0; jt < 16; ++jt) {
        const int cur = jt & 1;
        if (jt < 15) {
            stage_load(jt + 1);
            tnext = *reinterpret_cast<const f16x8*>(tdp + (jt + 1) * 32);
        }

        // ---- S^T = K * Q^T ----
        f32x4 s[2];
        __builtin_amdgcn_s_setprio(1);
#pragma unroll
        for (int fj = 0; fj < 2; ++fj) {
            f16x8 ka0 = *reinterpret_cast<const f16x8*>(&Ks[cur][half][kro0[fj]]);
            f16x8 ka1 = *reinterpret_cast<const f16x8*>(&Ks[cur][half][kro1[fj]]);
            f32x4 zz = {0.f, 0.f, 0.f, 0.f};
            zz = __builtin_amdgcn_mfma_f32_16x16x32_f16(ka0, qf[0], zz, 0, 0, 0);
            s[fj] = __builtin_amdgcn_mfma_f32_16x16x32_f16(ka1, qf[1], zz, 0, 0, 0);
        }
        __builtin_amdgcn_s_setprio(0);

        // ---- bias + per-lane max (no cross-lane in steady state) ----
        float pvv[2][4];
        float tmax = -1e30f;
#pragma unroll
        for (int fj = 0; fj < 2; ++fj)
#pragma unroll
            for (int e = 0; e < 4; ++e) {
                float u = (float)tcur[fj * 4 + e];
                float vsc;
                if (lin) {
                    vsc = fmaf(u, cH, s[fj][e] + dH);
                } else {
                    float x = fminf(fmaxf(u, 0.f), 1.f) * 1024.f;
                    int ix = (int)x;
                    ix = (ix > 1023) ? 1023 : ix;
                    float fr = x - (float)ix;
                    float t0v = th[ix], t1v = th[ix + 1];
                    vsc = s[fj][e] + fmaf(fr, t1v - t0v, t0v);
                }
                pvv[fj][e] = vsc;
                tmax = fmaxf(tmax, vsc);
            }

        // deferred-max: only reduce+rescale when some lane exceeds mr + 8
        if (__any(tmax > mr + 8.f)) {
            tmax = fmaxf(tmax, __shfl_xor(tmax, 16));
            tmax = fmaxf(tmax, __shfl_xor(tmax, 32));
            if (tmax > mr) {
                float alpha = exp2f(mr - tmax);
                mr = tmax;
                lrp *= alpha;
#pragma unroll
                for (int fv = 0; fv < 4; ++fv) o[fv] *= alpha;
            }
        }

        // exp2 (bounded by 2^8), lane-partial l, pack P
        f16x4 pq[2];
#pragma unroll
        for (int fj = 0; fj < 2; ++fj)
#pragma unroll
            for (int e = 0; e < 4; ++e) {
                float p = exp2f(pvv[fj][e] - mr);
                lrp += p;
                pq[fj][e] = (f16)p;
            }

        f16* ps = Ps[w];
        *reinterpret_cast<f16x4*>(ps + pw0) = pq[0];
        *reinterpret_cast<f16x4*>(ps + pw1) = pq[1];
        f16x8 pb = *reinterpret_cast<const f16x8*>(ps + prd);

        // ---- out^T += V^T * P^T ----
        __builtin_amdgcn_s_setprio(1);
#pragma unroll
        for (int fv = 0; fv < 4; ++fv) {
            f16x8 va = *reinterpret_cast<const f16x8*>(&Vs[cur][half][vro[fv]]);
            o[fv] = __builtin_amdgcn_mfma_f32_16x16x32_f16(va, pb, o[fv], 0, 0, 0);
        }
        __builtin_amdgcn_s_setprio(0);

        if (jt < 15) stage_write(cur ^ 1);
        __syncthreads();
        tcur = tnext;
    }

    // epilogue cross-lane l reduction (lanes i16, +16, +32, +48 share a row)
    float lr = lrp;
    lr += __shfl_xor(lr, 16);
    lr += __shfl_xor(lr, 32);

    // ---- merge halves (flash-decoding combine), then store ----
    if (half == 1) {
#pragma unroll
        for (int fv = 0; fv < 4; ++fv)
            *reinterpret_cast<f32x4*>(&obuf[pr][i16][fv * 16 + g * 4]) = o[fv];
        if (g == 0) { mlb[pr][0][i16] = mr; mlb[pr][1][i16] = lr; }
    }
    __syncthreads();
    if (half == 0) {
        const float m1 = mlb[pr][0][i16], l1 = mlb[pr][1][i16];
        const float mm = fmaxf(mr, m1);
        const float a0 = exp2f(mr - mm), a1 = exp2f(m1 - mm);
        const float inv = 1.0f / (lr * a0 + l1 * a1);
#pragma unroll
        for (int fv = 0; fv < 4; ++fv) {
            f32x4 o1 = *reinterpret_cast<const f32x4*>(&obuf[pr][i16][fv * 16 + g * 4]);
            f16x4 hv;
#pragma unroll
            for (int e = 0; e < 4; ++e) hv[e] = (f16)((o[fv][e] * a0 + o1[e] * a1) * inv);
            *reinterpret_cast<f16x4*>(
                out16 + (size_t)(b * S + qrow) * D + h * 64 + fv * 16 + g * 4) = hv;
        }
    }
}

// ---------------------------------------------------------------------------
// Kernel 4: output projection (unchanged).
// ---------------------------------------------------------------------------
__global__ __launch_bounds__(256) void final_gemm(const f16* __restrict__ A, const f16* __restrict__ WoT,
                                                  const float* __restrict__ bo, float* __restrict__ out)
{
    __shared__ f16 As[2][64][40];
    __shared__ f16 Bs[2][64][40];

    const int t = threadIdx.x;
    const int l = t & 63, w = t >> 6;
    const int i16 = l & 15, g = l >> 4;
    const int wm = w >> 1, wn = w & 1;
    const int m0 = blockIdx.x * 64, n0 = blockIdx.y * 64;

    f32x4 acc[2][2] = {};
    f16x8 ar, br;
    const int srow = t >> 2, sc8 = t & 3;

    auto load_stage = [&](int kt) {
        const int k0 = kt * 32;
        ar = *reinterpret_cast<const f16x8*>(A + (size_t)(m0 + srow) * D + k0 + sc8 * 8);
        br = *reinterpret_cast<const f16x8*>(WoT + (size_t)(n0 + srow) * D + k0 + sc8 * 8);
    };
    auto write_stage = [&](int buf) {
        *reinterpret_cast<f16x8*>(&As[buf][srow][sc8 * 8]) = ar;
        *reinterpret_cast<f16x8*>(&Bs[buf][srow][sc8 * 8]) = br;
    };

    load_stage(0);
    write_stage(0);
    __syncthreads();

    for (int kt = 0; kt < 16; ++kt) {
        const int cur = kt & 1;
        if (kt < 15) load_stage(kt + 1);

        f16x8 af[2], bf[2];
#pragma unroll
        for (int i = 0; i < 2; ++i)
            af[i] = *reinterpret_cast<const f16x8*>(&As[cur][wm * 32 + i * 16 + i16][g * 8]);
#pragma unroll
        for (int j = 0; j < 2; ++j)
            bf[j] = *reinterpret_cast<const f16x8*>(&Bs[cur][wn * 32 + j * 16 + i16][g * 8]);
#pragma unroll
        for (int i = 0; i < 2; ++i)
#pragma unroll
            for (int j = 0; j < 2; ++j)
                acc[i][j] = __builtin_amdgcn_mfma_f32_16x16x32_f16(af[i], bf[j], acc[i][j], 0, 0, 0);

        if (kt < 15) write_stage(cur ^ 1);
        __syncthreads();
    }

    float bvv[2];
#pragma unroll
    for (int j = 0; j < 2; ++j) bvv[j] = bo[n0 + wn * 32 + j * 16 + i16];

#pragma unroll
    for (int i = 0; i < 2; ++i) {
#pragma unroll
        for (int j = 0; j < 2; ++j) {
            const int nn = n0 + wn * 32 + j * 16 + i16;
#pragma unroll
            for (int e = 0; e < 4; ++e) {
                const int mr = m0 + wm * 32 + i * 16 + g * 4 + e;
                out[(size_t)mr * D + nn] = acc[i][j][e] + bvv[j];
            }
        }
    }
}

// ---------------------------------------------------------------------------
extern "C" void kernel_launch(void* const* d_in, const int* in_sizes, int n_in,
                              void* d_out, int out_size, void* d_ws, size_t ws_size,
                              hipStream_t stream)
{
    (void)in_sizes; (void)n_in; (void)out_size; (void)ws_size; // needs ~28 MB of ws

    const float* query = (const float*)d_in[0];
    const float* key_  = (const float*)d_in[1];
    const float* value = (const float*)d_in[2];
    const float* td    = (const float*)d_in[3];
    const float* Wq  = (const float*)d_in[4];  const float* bq  = (const float*)d_in[5];
    const float* Wk  = (const float*)d_in[6];  const float* bk  = (const float*)d_in[7];
    const float* Wv  = (const float*)d_in[8];  const float* bv  = (const float*)d_in[9];
    const float* Wo  = (const float*)d_in[10]; const float* bo  = (const float*)d_in[11];
    const float* Wt1 = (const float*)d_in[12]; const float* bt1 = (const float*)d_in[13];
    const float* Wt2 = (const float*)d_in[14]; const float* bt2 = (const float*)d_in[15];
    float* out = (float*)d_out;

    char* ws = (char*)d_ws;
    f16*   WT   = (f16*)(ws + OFF_WT);
    f16*   q16  = (f16*)(ws + OFF_Q16);
    f16*   k16  = (f16*)(ws + OFF_K16);
    f16*   vT   = (f16*)(ws + OFF_VT);
    f16*   at16 = (f16*)(ws + OFF_AT);
    float* tab  = (float*)(ws + OFF_TAB);
    float* coef = (float*)(ws + OFF_COEF);
    f16*   tdh  = (f16*)(ws + OFF_TDH);

    prep_small<<<257, 256, 0, stream>>>(Wq, Wk, Wv, Wo, WT,
                                        Wt1, bt1, Wt2, bt2, tab, coef);
    proj_plus<<<2432, 256, 0, stream>>>(query, key_, value, WT, bq, bk, bv,
                                        q16, k16, vT, 0.125f * L2E, td, tdh);
    attn_kernel<<<512, 512, 0, stream>>>(q16, k16, vT, tdh, tab, coef, at16);
    final_gemm<<<dim3(64, 8), 256, 0, stream>>>(at16, WT + 3ull * (size_t)D * D, bo, out);
}